// Round 1
// 100.933 us; speedup vs baseline: 1.0318x; 1.0318x over previous
//
#include <hip/hip_runtime.h>
#include <math.h>

#define B_    16
#define N_    128
#define F_IN_ 8
#define S_    8
#define F_OUT_ 64
#define KN_HID_ 32
#define FC_HID_ 32

// workspace layout (float offsets)
//  nodes: [B*N][F_OUT] = 131072  (post-relu node features, pooled by k3)
#define NODE_OFF  0

// walk the 2x64-bit adjacency mask (wave-uniform); returns -1 when empty
__device__ __forceinline__ int next_edge(unsigned long long& lo,
                                         unsigned long long& hi) {
    if (lo) { int i = __builtin_ctzll(lo); lo &= lo - 1; return i; }
    if (hi) { int i = __builtin_ctzll(hi) + 64; hi &= hi - 1; return i; }
    return -1;
}

// ---------------------------------------------------------------------------
// k2: fused ECCConv via the T-factorization. ONE NODE PER WAVE (8 waves/CU).
//   T[k,f]  = sum_{i active} h[b,n,i,k] * X[b,i,f]   (32x8 per node)
//   T[32,f] = sum_{i active} X[b,i,f]                (bias row)
//   node[o] = relu( sum_{kf} T[kf]*w2ext[kf,o] + X[b,n]@root_w + conv_b )
// NEW vs prior round: E[bn,:,:] (4 KB) is bulk-staged to wave-private LDS
// up front (one ~500cy latency exposure, overlapped with ballot/setup)
// instead of ~13 scattered 32B global reads inside the edge loop. Edge loop
// is now 2 uniform ds_read_b128 broadcasts + FMA tree — no shfl chain.
// Grid: 512 blocks x 256 thr; block = 4 nodes (same batch), wave = 1 node.
// ---------------------------------------------------------------------------
__global__ __launch_bounds__(256) void k2_fused(
    const float* __restrict__ A, const float* __restrict__ X,
    const float* __restrict__ E,
    const float* __restrict__ kn_w1, const float* __restrict__ kn_b1,
    const float* __restrict__ kn_w2, const float* __restrict__ kn_b2,
    const float* __restrict__ root_w, const float* __restrict__ conv_b,
    float* __restrict__ ws)
{
    __shared__ float Xlds[N_ * F_IN_];          // 4 KB, whole X row of batch b
    __shared__ float Elds[4][N_ * S_];          // 16 KB, E row-block per wave
    __shared__ float Tlds[4][264];              // 4.2 KB (one T per wave)

    const int t    = threadIdx.x;
    const int lane = t & 63;
    const int wave = t >> 6;
    const int h2   = lane >> 5;                 // f-group: 0 -> f 0..3, 1 -> 4..7
    const int j    = lane & 31;                 // h index this lane owns
    const int b    = blockIdx.x >> 5;           // 32 blocks per batch
    const int bn   = blockIdx.x * 4 + wave;     // this wave's node

    // stage X[b,:,:] (4 KB) once per block
    ((float4*)Xlds)[t] = ((const float4*)(X + b * N_ * F_IN_))[t];

    // stage E[bn,:,:] (4 KB) into this wave's private LDS slab.
    // Coalesced: 4 x float4 per lane. Latency of these loads overlaps the
    // A-row read + ballot + kn_w1 setup below; same-wave write->read means
    // no barrier needed (compiler inserts vmcnt/lgkmcnt waits).
    {
        const float4* __restrict__ src = (const float4*)(E + (size_t)bn * N_ * S_);
        float4* __restrict__ dst = (float4*)Elds[wave];
#pragma unroll
        for (int r = 0; r < 4; ++r)
            dst[lane + 64 * r] = src[lane + 64 * r];
    }

    // per-lane column j of kn_w1
    float w1j[S_];
#pragma unroll
    for (int s = 0; s < S_; ++s) w1j[s] = kn_w1[s * KN_HID_ + j];
    const float b1j = kn_b1[j];

    // adjacency row -> wave-uniform masks
    const float a0 = A[(size_t)bn * N_ + lane];
    const float a1 = A[(size_t)bn * N_ + 64 + lane];
    unsigned long long mlo = __ballot(a0 != 0.f);
    unsigned long long mhi = __ballot(a1 != 0.f);

    __syncthreads();   // Xlds cross-wave visibility

    const float4* __restrict__ Xl4 = (const float4*)Xlds;
    const float4* __restrict__ El4 = (const float4*)Elds[wave];

    // ---- edge phase: LDS-resident E, depth-2 prefetch ----------------------
    float T[4]  = {0.f, 0.f, 0.f, 0.f};
    float xs[4] = {0.f, 0.f, 0.f, 0.f};

    int i0 = next_edge(mlo, mhi);
    float4 eA0, eA1;
    if (i0 >= 0) { eA0 = El4[i0 * 2]; eA1 = El4[i0 * 2 + 1]; }
    int i1 = (i0 >= 0) ? next_edge(mlo, mhi) : -1;
    float4 eB0, eB1;
    if (i1 >= 0) { eB0 = El4[i1 * 2]; eB1 = El4[i1 * 2 + 1]; }

    while (i0 >= 0) {
        // prefetch edge i+2 (uniform-address LDS broadcast, conflict-free)
        const int i2 = (i1 >= 0) ? next_edge(mlo, mhi) : -1;
        float4 eC0, eC1;
        if (i2 >= 0) { eC0 = El4[i2 * 2]; eC1 = El4[i2 * 2 + 1]; }

        // h[j] = relu(E[bn,i0,:] . w1[:,j] + b1[j]) — two 4-FMA trees
        const float ha = fmaf(eA0.x, w1j[0], fmaf(eA0.y, w1j[1],
                         fmaf(eA0.z, w1j[2], eA0.w * w1j[3])));
        const float hb = fmaf(eA1.x, w1j[4], fmaf(eA1.y, w1j[5],
                         fmaf(eA1.z, w1j[6], eA1.w * w1j[7])));
        float hv = b1j + ha + hb;
        hv = hv > 0.f ? hv : 0.f;

        const float4 xf = Xl4[i0 * 2 + h2];     // LDS broadcast
        T[0] = fmaf(hv, xf.x, T[0]);  T[1] = fmaf(hv, xf.y, T[1]);
        T[2] = fmaf(hv, xf.z, T[2]);  T[3] = fmaf(hv, xf.w, T[3]);
        xs[0] += xf.x; xs[1] += xf.y; xs[2] += xf.z; xs[3] += xf.w;

        i0 = i1; eA0 = eB0; eA1 = eB1;
        i1 = i2; eB0 = eC0; eB1 = eC1;
    }

    // T[k,f] -> LDS at kf = k*8+f; bias row kf = 256..263
    float4* __restrict__ Tl4 = (float4*)Tlds[wave];
    Tl4[j * 2 + h2] = make_float4(T[0], T[1], T[2], T[3]);
    if (j == 0)
        Tl4[64 + h2] = make_float4(xs[0], xs[1], xs[2], xs[3]);
    // same-wave LDS write->read: compiler inserts lgkmcnt waits, no barrier

    // ---- contraction: lane=(g,q); o in [4q,4q+4), kf = g,g+4,... -----------
    const int q = lane & 15;
    const int g = lane >> 4;
    const float* __restrict__ T0 = Tlds[wave];
    const float4* __restrict__ W4 = (const float4*)kn_w2;
    const float4* __restrict__ B4 = (const float4*)kn_b2;

    float4 acc = make_float4(0.f, 0.f, 0.f, 0.f);
#pragma unroll 8
    for (int kf = g; kf < 256; kf += 4) {
        const float4 w = W4[kf * 16 + q];       // coalesced 16B, L1-hot
        const float t0 = T0[kf];                // 4 addrs -> LDS broadcast
        acc.x += t0 * w.x; acc.y += t0 * w.y; acc.z += t0 * w.z; acc.w += t0 * w.w;
    }
#pragma unroll
    for (int f = g; f < F_IN_; f += 4) {
        const float4 w = B4[f * 16 + q];
        const float t0 = T0[256 + f];
        acc.x += t0 * w.x; acc.y += t0 * w.y; acc.z += t0 * w.z; acc.w += t0 * w.w;
    }

    // butterfly-reduce over g (lanes q, q+16, q+32, q+48)
#pragma unroll
    for (int d = 16; d < 64; d <<= 1) {
        acc.x += __shfl_xor(acc.x, d); acc.y += __shfl_xor(acc.y, d);
        acc.z += __shfl_xor(acc.z, d); acc.w += __shfl_xor(acc.w, d);
    }

    // ---- epilogue: + X[b,n]@root_w + conv_b, relu, store (g==0 lanes) ------
    const float4* __restrict__ R4 = (const float4*)root_w;
    const float4 cb = ((const float4*)conv_b)[q];
    const int n = bn & (N_ - 1);
    float4 r = acc;
    r.x += cb.x; r.y += cb.y; r.z += cb.z; r.w += cb.w;
#pragma unroll
    for (int f = 0; f < F_IN_; ++f) {
        const float xv = Xlds[n * F_IN_ + f];
        const float4 rw = R4[f * 16 + q];
        r.x += xv * rw.x; r.y += xv * rw.y; r.z += xv * rw.z; r.w += xv * rw.w;
    }
    r.x = r.x > 0.f ? r.x : 0.f;  r.y = r.y > 0.f ? r.y : 0.f;
    r.z = r.z > 0.f ? r.z : 0.f;  r.w = r.w > 0.f ? r.w : 0.f;
    if (g == 0)
        ((float4*)(ws + NODE_OFF + (size_t)bn * F_OUT_))[q] = r;
}

// ---------------------------------------------------------------------------
// k3: pooling + head. One 256-thread block per batch element.
// ---------------------------------------------------------------------------
__global__ __launch_bounds__(256) void k3_head(
    const float* __restrict__ fc_w, const float* __restrict__ fc_b,
    const float* __restrict__ out_w, const float* __restrict__ out_b,
    const float* __restrict__ ws, float* __restrict__ out)
{
    const int b = blockIdx.x;
    const int t = threadIdx.x;
    const int o = t & 63;
    const int g = t >> 6;

    float p = 0.f;
    for (int n = g; n < N_; n += 4)
        p += ws[NODE_OFF + (size_t)(b * N_ + n) * F_OUT_ + o];

    __shared__ float red[4][F_OUT_];
    __shared__ float pm[F_OUT_];
    __shared__ float y[FC_HID_];
    red[g][o] = p;
    __syncthreads();

    if (t < F_OUT_)
        pm[t] = (red[0][t] + red[1][t] + red[2][t] + red[3][t]) * (1.0f / (float)N_);
    __syncthreads();

    if (t < FC_HID_) {
        float v = fc_b[t];
#pragma unroll
        for (int o2 = 0; o2 < F_OUT_; ++o2) v += pm[o2] * fc_w[o2 * FC_HID_ + t];
        y[t] = v > 0.f ? v : 0.f;
    }
    __syncthreads();

    if (t == 0) {
        float z = out_b[0];
#pragma unroll
        for (int qq = 0; qq < FC_HID_; ++qq) z += y[qq] * out_w[qq];
        out[b] = 1.f / (1.f + expf(-z));
    }
}

extern "C" void kernel_launch(void* const* d_in, const int* in_sizes, int n_in,
                              void* d_out, int out_size, void* d_ws, size_t ws_size,
                              hipStream_t stream)
{
    const float* A      = (const float*)d_in[0];
    const float* X      = (const float*)d_in[1];
    const float* E      = (const float*)d_in[2];
    const float* kn_w1  = (const float*)d_in[3];
    const float* kn_b1  = (const float*)d_in[4];
    const float* kn_w2  = (const float*)d_in[5];
    const float* kn_b2  = (const float*)d_in[6];
    const float* root_w = (const float*)d_in[7];
    const float* conv_b = (const float*)d_in[8];
    const float* fc_w   = (const float*)d_in[9];
    const float* fc_b   = (const float*)d_in[10];
    const float* out_w  = (const float*)d_in[11];
    const float* out_b  = (const float*)d_in[12];

    float* ws  = (float*)d_ws;
    float* out = (float*)d_out;

    k2_fused<<<B_ * N_ / 4, 256, 0, stream>>>(A, X, E, kn_w1, kn_b1,
                                              kn_w2, kn_b2, root_w, conv_b, ws);
    k3_head<<<B_, 256, 0, stream>>>(fc_w, fc_b, out_w, out_b, ws, out);
}

// Round 2
// 95.309 us; speedup vs baseline: 1.0927x; 1.0590x over previous
//
#include <hip/hip_runtime.h>
#include <math.h>

#define B_    16
#define N_    128
#define F_IN_ 8
#define S_    8
#define F_OUT_ 64
#define KN_HID_ 32
#define FC_HID_ 32

// workspace layout (float offsets)
//  pooled block partials: [256 blocks][F_OUT] = 16384 floats
#define NODE_OFF  0

// walk the 2x64-bit adjacency mask (wave-uniform); returns -1 when empty
__device__ __forceinline__ int next_edge(unsigned long long& lo,
                                         unsigned long long& hi) {
    if (lo) { int i = __builtin_ctzll(lo); lo &= lo - 1; return i; }
    if (hi) { int i = __builtin_ctzll(hi) + 64; hi &= hi - 1; return i; }
    return -1;
}

// ---------------------------------------------------------------------------
// k2: fused ECCConv. 512 threads = 8 waves = 8 nodes per block; grid 256
// (= 1 block/CU, 8 waves/CU — same occupancy as before).
// Edge phase (per wave, own node): LDS-resident E, depth-2 prefetch,
//   T[k,f] = sum_i h[i,k]*X[i,f]; bias row = sum_i X[i,f].
// NEW: block-cooperative contraction. All 8 T's live in shared LDS; wave w
// owns a 33-row slice of w2ext (32 rows of kn_w2 + bias row f=w) and
// contracts it against ALL EIGHT nodes. w2ext (66 KB > L1) is now streamed
// from L2 once per BLOCK instead of once per wave: 135 MB -> 17 MB total,
// removing the ~3.5x L2-BW stall. Cross-wave partials reduced via LDS.
// Block then pools its 8 relu'd node vectors locally -> one 64-float
// partial per block in ws (k3 traffic /8).
// ---------------------------------------------------------------------------
__global__ __launch_bounds__(512) void k2_fused(
    const float* __restrict__ A, const float* __restrict__ X,
    const float* __restrict__ E,
    const float* __restrict__ kn_w1, const float* __restrict__ kn_b1,
    const float* __restrict__ kn_w2, const float* __restrict__ kn_b2,
    const float* __restrict__ root_w, const float* __restrict__ conv_b,
    float* __restrict__ ws)
{
    __shared__ float Xlds[N_ * F_IN_];          // 4 KB, whole X row of batch b
    __shared__ float Elds[8][N_ * S_];          // 32 KB, E row-block per wave
    __shared__ float Tlds[8][264];              // 8.25 KB, T per node (shared!)
    __shared__ float Red[8][8][F_OUT_];         // 16 KB [src wave][node][o]
    __shared__ float Pool[8][F_OUT_];           // 2 KB relu'd node vectors

    const int t    = threadIdx.x;
    const int lane = t & 63;
    const int wave = t >> 6;                    // 0..7 = node-within-block
    const int h2   = lane >> 5;                 // f-group: 0 -> f 0..3, 1 -> 4..7
    const int j    = lane & 31;                 // h index this lane owns
    const int b    = blockIdx.x >> 4;           // 16 blocks per batch
    const int bn   = blockIdx.x * 8 + wave;     // this wave's node (b*128+n)

    // stage X[b,:,:] (4 KB) once per block: 512 x float2
    ((float2*)Xlds)[t] = ((const float2*)(X + b * N_ * F_IN_))[t];

    // stage E[bn,:,:] (4 KB) into this wave's private slab (coalesced float4)
    {
        const float4* __restrict__ src = (const float4*)(E + (size_t)bn * N_ * S_);
        float4* __restrict__ dst = (float4*)Elds[wave];
#pragma unroll
        for (int r = 0; r < 4; ++r)
            dst[lane + 64 * r] = src[lane + 64 * r];
    }

    // per-lane column j of kn_w1
    float w1j[S_];
#pragma unroll
    for (int s = 0; s < S_; ++s) w1j[s] = kn_w1[s * KN_HID_ + j];
    const float b1j = kn_b1[j];

    // adjacency row -> wave-uniform masks
    const float a0 = A[(size_t)bn * N_ + lane];
    const float a1 = A[(size_t)bn * N_ + 64 + lane];
    unsigned long long mlo = __ballot(a0 != 0.f);
    unsigned long long mhi = __ballot(a1 != 0.f);

    __syncthreads();   // Xlds cross-wave visibility

    const float4* __restrict__ Xl4 = (const float4*)Xlds;
    const float4* __restrict__ El4 = (const float4*)Elds[wave];

    // ---- edge phase: LDS-resident E, depth-2 prefetch ----------------------
    float T[4]  = {0.f, 0.f, 0.f, 0.f};
    float xs[4] = {0.f, 0.f, 0.f, 0.f};

    int i0 = next_edge(mlo, mhi);
    float4 eA0, eA1;
    if (i0 >= 0) { eA0 = El4[i0 * 2]; eA1 = El4[i0 * 2 + 1]; }
    int i1 = (i0 >= 0) ? next_edge(mlo, mhi) : -1;
    float4 eB0, eB1;
    if (i1 >= 0) { eB0 = El4[i1 * 2]; eB1 = El4[i1 * 2 + 1]; }

    while (i0 >= 0) {
        // prefetch edge i+2 (uniform-address LDS broadcast, conflict-free)
        const int i2 = (i1 >= 0) ? next_edge(mlo, mhi) : -1;
        float4 eC0, eC1;
        if (i2 >= 0) { eC0 = El4[i2 * 2]; eC1 = El4[i2 * 2 + 1]; }

        // h[j] = relu(E[bn,i0,:] . w1[:,j] + b1[j]) — two 4-FMA trees
        const float ha = fmaf(eA0.x, w1j[0], fmaf(eA0.y, w1j[1],
                         fmaf(eA0.z, w1j[2], eA0.w * w1j[3])));
        const float hb = fmaf(eA1.x, w1j[4], fmaf(eA1.y, w1j[5],
                         fmaf(eA1.z, w1j[6], eA1.w * w1j[7])));
        float hv = b1j + ha + hb;
        hv = hv > 0.f ? hv : 0.f;

        const float4 xf = Xl4[i0 * 2 + h2];     // LDS broadcast
        T[0] = fmaf(hv, xf.x, T[0]);  T[1] = fmaf(hv, xf.y, T[1]);
        T[2] = fmaf(hv, xf.z, T[2]);  T[3] = fmaf(hv, xf.w, T[3]);
        xs[0] += xf.x; xs[1] += xf.y; xs[2] += xf.z; xs[3] += xf.w;

        i0 = i1; eA0 = eB0; eA1 = eB1;
        i1 = i2; eB0 = eC0; eB1 = eC1;
    }

    // T[k,f] -> LDS at kf = k*8+f; bias row kf = 256..263
    float4* __restrict__ Tl4 = (float4*)Tlds[wave];
    Tl4[j * 2 + h2] = make_float4(T[0], T[1], T[2], T[3]);
    if (j == 0)
        Tl4[64 + h2] = make_float4(xs[0], xs[1], xs[2], xs[3]);

    __syncthreads();   // T cross-wave visibility (contraction reads all 8)

    // ---- cooperative contraction: wave w owns w2ext rows [32w, 32w+32) + bias f=w
    // lane=(g,q): o in [4q,4q+4), kf2 = g, g+4, ..., 28+g (8 iters)
    const int q = lane & 15;
    const int g = lane >> 4;
    const float4* __restrict__ W4 = (const float4*)kn_w2;
    const float4* __restrict__ B4 = (const float4*)kn_b2;
    const int base = wave * 32;

    float4 acc[8];
#pragma unroll
    for (int nd = 0; nd < 8; ++nd) acc[nd] = make_float4(0.f, 0.f, 0.f, 0.f);

#pragma unroll
    for (int kf2 = g; kf2 < 32; kf2 += 4) {
        const int kf = base + kf2;
        const float4 w = W4[kf * 16 + q];       // coalesced 16B, once per block
#pragma unroll
        for (int nd = 0; nd < 8; ++nd) {
            const float tv = Tlds[nd][kf];      // LDS broadcast (16 lanes/addr)
            acc[nd].x = fmaf(tv, w.x, acc[nd].x);
            acc[nd].y = fmaf(tv, w.y, acc[nd].y);
            acc[nd].z = fmaf(tv, w.z, acc[nd].z);
            acc[nd].w = fmaf(tv, w.w, acc[nd].w);
        }
    }
    if (g == 0) {                               // bias row f = wave
        const float4 w = B4[wave * 16 + q];
#pragma unroll
        for (int nd = 0; nd < 8; ++nd) {
            const float tv = Tlds[nd][256 + wave];
            acc[nd].x = fmaf(tv, w.x, acc[nd].x);
            acc[nd].y = fmaf(tv, w.y, acc[nd].y);
            acc[nd].z = fmaf(tv, w.z, acc[nd].z);
            acc[nd].w = fmaf(tv, w.w, acc[nd].w);
        }
    }

    // butterfly-reduce over g (lanes q, q+16, q+32, q+48) for all 8 nodes
#pragma unroll
    for (int d = 16; d < 64; d <<= 1) {
#pragma unroll
        for (int nd = 0; nd < 8; ++nd) {
            acc[nd].x += __shfl_xor(acc[nd].x, d);
            acc[nd].y += __shfl_xor(acc[nd].y, d);
            acc[nd].z += __shfl_xor(acc[nd].z, d);
            acc[nd].w += __shfl_xor(acc[nd].w, d);
        }
    }

    // g==0 lanes publish this wave's kf-slice partials for all 8 nodes
    if (g == 0) {
#pragma unroll
        for (int nd = 0; nd < 8; ++nd)
            ((float4*)Red[wave][nd])[q] = acc[nd];  // 256B contiguous, 2-way free
    }
    __syncthreads();

    // ---- node-final: wave w sums 8 slice-partials for its own node,
    //      adds root term + bias, relu, stages into Pool
    if (g == 0) {
        const float4 cb = ((const float4*)conv_b)[q];
        float4 r = cb;
#pragma unroll
        for (int pw = 0; pw < 8; ++pw) {
            const float4 p = ((const float4*)Red[pw][wave])[q];
            r.x += p.x; r.y += p.y; r.z += p.z; r.w += p.w;
        }
        const int n = bn & (N_ - 1);
        const float4* __restrict__ R4 = (const float4*)root_w;
#pragma unroll
        for (int f = 0; f < F_IN_; ++f) {
            const float xv = Xlds[n * F_IN_ + f];
            const float4 rw = R4[f * 16 + q];
            r.x = fmaf(xv, rw.x, r.x); r.y = fmaf(xv, rw.y, r.y);
            r.z = fmaf(xv, rw.z, r.z); r.w = fmaf(xv, rw.w, r.w);
        }
        r.x = r.x > 0.f ? r.x : 0.f;  r.y = r.y > 0.f ? r.y : 0.f;
        r.z = r.z > 0.f ? r.z : 0.f;  r.w = r.w > 0.f ? r.w : 0.f;
        ((float4*)Pool[wave])[q] = r;
    }
    __syncthreads();

    // ---- block-level pool: wave 0 sums the 8 node vectors -> ws partial
    if (wave == 0) {
        float s = 0.f;
#pragma unroll
        for (int nd = 0; nd < 8; ++nd) s += Pool[nd][lane];
        ws[NODE_OFF + (size_t)blockIdx.x * F_OUT_ + lane] = s;
    }
}

// ---------------------------------------------------------------------------
// k3: pooling of 16 block-partials + head. One 256-thread block per batch.
// ---------------------------------------------------------------------------
__global__ __launch_bounds__(256) void k3_head(
    const float* __restrict__ fc_w, const float* __restrict__ fc_b,
    const float* __restrict__ out_w, const float* __restrict__ out_b,
    const float* __restrict__ ws, float* __restrict__ out)
{
    const int b = blockIdx.x;
    const int t = threadIdx.x;
    const int o = t & 63;
    const int g = t >> 6;

    float p = 0.f;
    for (int s = g; s < 16; s += 4)
        p += ws[NODE_OFF + (size_t)(b * 16 + s) * F_OUT_ + o];

    __shared__ float red[4][F_OUT_];
    __shared__ float pm[F_OUT_];
    __shared__ float y[FC_HID_];
    red[g][o] = p;
    __syncthreads();

    if (t < F_OUT_)
        pm[t] = (red[0][t] + red[1][t] + red[2][t] + red[3][t]) * (1.0f / (float)N_);
    __syncthreads();

    if (t < FC_HID_) {
        float v = fc_b[t];
#pragma unroll
        for (int o2 = 0; o2 < F_OUT_; ++o2) v += pm[o2] * fc_w[o2 * FC_HID_ + t];
        y[t] = v > 0.f ? v : 0.f;
    }
    __syncthreads();

    if (t == 0) {
        float z = out_b[0];
#pragma unroll
        for (int qq = 0; qq < FC_HID_; ++qq) z += y[qq] * out_w[qq];
        out[b] = 1.f / (1.f + expf(-z));
    }
}

extern "C" void kernel_launch(void* const* d_in, const int* in_sizes, int n_in,
                              void* d_out, int out_size, void* d_ws, size_t ws_size,
                              hipStream_t stream)
{
    const float* A      = (const float*)d_in[0];
    const float* X      = (const float*)d_in[1];
    const float* E      = (const float*)d_in[2];
    const float* kn_w1  = (const float*)d_in[3];
    const float* kn_b1  = (const float*)d_in[4];
    const float* kn_w2  = (const float*)d_in[5];
    const float* kn_b2  = (const float*)d_in[6];
    const float* root_w = (const float*)d_in[7];
    const float* conv_b = (const float*)d_in[8];
    const float* fc_w   = (const float*)d_in[9];
    const float* fc_b   = (const float*)d_in[10];
    const float* out_w  = (const float*)d_in[11];
    const float* out_b  = (const float*)d_in[12];

    float* ws  = (float*)d_ws;
    float* out = (float*)d_out;

    k2_fused<<<B_ * N_ / 8, 512, 0, stream>>>(A, X, E, kn_w1, kn_b1,
                                              kn_w2, kn_b2, root_w, conv_b, ws);
    k3_head<<<B_, 256, 0, stream>>>(fc_w, fc_b, out_w, out_b, ws, out);
}